// Round 6
// baseline (276.770 us; speedup 1.0000x reference)
//
#include <hip/hip_runtime.h>

#define BS 64
#define S  512
#define E  1024
#define H  16
#define HD 64
#define SCALE 0.125f   // 1/sqrt(64)
#define CATT 8         // attention chunks (64 rows each, 4 passes) — full-CU coverage w/ skip

// workspace float offsets
#define W_QKBF 66560      // bf16 qk (SCALE-folded): 64*16*1024 ushorts = 524288 float slots
#define W_NUM  1115136    // f32 numerator accumulator: BS*H*E floats (4 MB, L2-resident)
#define W_DEN  2163712    // f32 denominator accumulator: BS*H floats
#define W_CTX  2164736    // BS*E f32

typedef __attribute__((ext_vector_type(8))) short short8;
typedef __attribute__((ext_vector_type(4))) float floatx4;

union S8u { uint2 u2[2]; short8 s; };

__device__ __forceinline__ unsigned short bf16c(float x) {
    unsigned int u = __float_as_uint(x);
    return (unsigned short)((u + 0x7fffu + ((u >> 16) & 1u)) >> 16);
}
__device__ __forceinline__ unsigned int pack_bf16(float a, float b) {
    return (unsigned int)bf16c(a) | ((unsigned int)bf16c(b) << 16);
}
__device__ __forceinline__ void fma4(float4& acc, float s, const float4& v) {
    acc.x += s * v.x; acc.y += s * v.y; acc.z += s * v.z; acc.w += s * v.w;
}
__device__ __forceinline__ float dot4(const float4& a, const float4& b) {
    return a.x * b.x + a.y * b.y + a.z * b.z + a.w * b.w;
}
__device__ __forceinline__ void bfly8(float* a) {
    #pragma unroll
    for (int off = 32; off > 0; off >>= 1) {
        #pragma unroll
        for (int i = 0; i < 8; i++) a[i] += __shfl_xor(a[i], off, 64);
    }
}

// ---- 1. fused prep + q + qk -> qkbf; also zeroes the f32 accumulators ----
__global__ void k_qgen(const float* __restrict__ model, const float* __restrict__ knowledge,
                       const int* __restrict__ ids, const int* __restrict__ mask_id_p,
                       const int* __restrict__ kid_p, int* __restrict__ mp,
                       const float* __restrict__ w_in, const float* __restrict__ b_in,
                       unsigned short* __restrict__ qkbf,
                       float* __restrict__ num, float* __restrict__ den) {
    int h = blockIdx.x, b0 = blockIdx.y * 4, t = threadIdx.x;
    __shared__ float qin_l[4][1024];
    __shared__ float qred[4][64][4];
    __shared__ float qs_l[4][64];
    __shared__ int best[4];
    {   // zero f32 accumulators (kernel boundary orders these vs k_attn's atomics)
        float4 z = make_float4(0.f, 0.f, 0.f, 0.f);
        float4* nz = (float4*)num + (size_t)(blockIdx.y * H + h) * 1024;
        #pragma unroll
        for (int k = 0; k < 4; k++) nz[k * 256 + t] = z;
        if (h == 0 && t < 64) den[blockIdx.y * 64 + t] = 0.f;
    }
    if (t < 4) best[t] = S;
    __syncthreads();
    {   // scan: 64 threads per batch, 8 ids each
        int bb = t >> 6, ls = t & 63;
        int mid = mask_id_p[0];
        int found = S;
        #pragma unroll
        for (int k = 0; k < 8; k++) {
            int s = ls + k * 64;
            if (ids[(size_t)(b0 + bb) * S + s] == mid) found = min(found, s);
        }
        if (found < S) atomicMin(&best[bb], found);
    }
    __syncthreads();
    {   // gather q-input rows directly into LDS
        int kid = kid_p[0];
        #pragma unroll
        for (int bb = 0; bb < 4; bb++) {
            int m = (best[bb] == S) ? 0 : best[bb];
            bool isk = (ids[(size_t)(b0 + bb) * S + m] == kid);
            const float* qrow = isk ? knowledge + (size_t)(b0 + bb) * E
                                    : model + ((size_t)((b0 + bb) * S + m)) * E;
            *(float4*)&qin_l[bb][t * 4] = *(const float4*)(qrow + t * 4);
        }
        if (h == 0 && t < 4) mp[b0 + t] = (best[t] == S) ? 0 : best[t];
    }
    __syncthreads();
    {
        int d = t >> 2, part = t & 3;
        const float* wr = w_in + (size_t)(h * HD + d) * E + part * 256;
        float acc[4] = {0.f, 0.f, 0.f, 0.f};
        #pragma unroll 8
        for (int i = 0; i < 64; i++) {
            float4 wv = *(const float4*)(wr + i * 4);
            #pragma unroll
            for (int bb = 0; bb < 4; bb++)
                acc[bb] += dot4(wv, *(const float4*)&qin_l[bb][part * 256 + i * 4]);
        }
        #pragma unroll
        for (int bb = 0; bb < 4; bb++) qred[bb][d][part] = acc[bb];
    }
    __syncthreads();
    if (t < 64) {
        float bias = b_in[h * HD + t];
        #pragma unroll
        for (int bb = 0; bb < 4; bb++)
            qs_l[bb][t] = qred[bb][t][0] + qred[bb][t][1] + qred[bb][t][2] + qred[bb][t][3] + bias;
    }
    __syncthreads();
    {
        int e0 = t * 4;
        const float* wk = w_in + (size_t)(E + h * HD) * E + e0;
        float4 acc[4];
        #pragma unroll
        for (int bb = 0; bb < 4; bb++) acc[bb] = make_float4(0.f, 0.f, 0.f, 0.f);
        #pragma unroll 8
        for (int d = 0; d < HD; d++) {
            float4 wv = *(const float4*)(wk + (size_t)d * E);
            #pragma unroll
            for (int bb = 0; bb < 4; bb++) fma4(acc[bb], qs_l[bb][d], wv);
        }
        #pragma unroll
        for (int bb = 0; bb < 4; bb++) {
            uint2 pk;
            pk.x = pack_bf16(acc[bb].x * SCALE, acc[bb].y * SCALE);
            pk.y = pack_bf16(acc[bb].z * SCALE, acc[bb].w * SCALE);
            *(uint2*)&qkbf[((size_t)(b0 + bb) * H + h) * E + e0] = pk;
        }
    }
}

// ---- 2. fused attention via MFMA; f32 atomic accumulation, empty-skip ----
// block per (chunk c of 64 rows, batch b); 512 thr (8 waves); 4 passes x 16 rows.
__global__ __launch_bounds__(512, 4) void k_attn(
    const float* __restrict__ model, const float* __restrict__ knowledge,
    const int* __restrict__ ids, const int* __restrict__ kid_p,
    const int* __restrict__ empty,
    const unsigned short* __restrict__ qkbf, float* __restrict__ num,
    float* __restrict__ den) {
    int c = blockIdx.x, b = blockIdx.y;
    if (empty[b]) return;   // uniform exit before any barrier: result is discarded by k_out

    __shared__ __align__(16) unsigned char Ubuf[73984];   // Rbuf(33024)+RbufT(40960)
    unsigned short* Rbuf  = (unsigned short*)Ubuf;           // 16 rows x 1032 (GEMM1 A)
    unsigned short* RbufT = (unsigned short*)(Ubuf + 33024); // 1024 e x 20 (GEMM2 B)
    __shared__ unsigned short Pbuf[16 * 40];
    __shared__ float Sred[4][16][17];
    __shared__ float denp[4][16];
    __shared__ unsigned long long kmask_s;

    int tid = threadIdx.x;
    int w = tid >> 6, l = tid & 63;
    int quad = l >> 4, lm = l & 15;
    int s0 = c * 64;

    if (w == 0) {
        int id = ids[b * S + s0 + l];
        unsigned long long mk = __ballot(id == kid_p[0]);
        if (l == 0) kmask_s = mk;
    }
    floatx4 accn[8];
    #pragma unroll
    for (int i = 0; i < 8; i++) accn[i] = (floatx4)0.f;
    float accden = 0.f;
    const float* kb = knowledge + (size_t)b * E;
    const float* mb = model + (size_t)b * S * E;
    const unsigned short* qh = qkbf + ((size_t)b * H + lm) * E;
    __syncthreads();
    unsigned long long kmask = kmask_s;

    // staging geometry: thread owns (row-group rgA, rgA+2) x col-quad c4
    int rgA = tid >> 8;        // 0 or 1
    int c4  = tid & 255;       // float4 column index

    float4 st[8];              // 2 units x 4 rows, held across compute (T14)

    auto ISSUE = [&](int pass) {
        int rb = pass * 16;
        #pragma unroll
        for (int j = 0; j < 4; j++) {
            int row = rb + rgA * 4 + j;
            const float* rp = ((kmask >> row) & 1ull) ? kb : mb + (size_t)(s0 + row) * E;
            st[j] = *(const float4*)(rp + c4 * 4);
        }
        #pragma unroll
        for (int j = 0; j < 4; j++) {
            int row = rb + (rgA + 2) * 4 + j;
            const float* rp = ((kmask >> row) & 1ull) ? kb : mb + (size_t)(s0 + row) * E;
            st[4 + j] = *(const float4*)(rp + c4 * 4);
        }
    };
    auto STORE = [&]() {
        #pragma unroll
        for (int u = 0; u < 2; u++) {
            int rg = rgA + u * 2;
            unsigned short hh[4][4];
            #pragma unroll
            for (int j = 0; j < 4; j++) {
                float4 v = st[u * 4 + j];
                hh[j][0] = bf16c(v.x); hh[j][1] = bf16c(v.y);
                hh[j][2] = bf16c(v.z); hh[j][3] = bf16c(v.w);
            }
            #pragma unroll
            for (int j = 0; j < 4; j++) {          // row-major Rbuf: 4 consecutive cols
                uint2 pk;
                pk.x = (unsigned int)hh[j][0] | ((unsigned int)hh[j][1] << 16);
                pk.y = (unsigned int)hh[j][2] | ((unsigned int)hh[j][3] << 16);
                *(uint2*)&Rbuf[(rg * 4 + j) * 1032 + c4 * 4] = pk;
            }
            #pragma unroll
            for (int k = 0; k < 4; k++) {          // transposed RbufT: 4 consecutive rows
                uint2 pk;
                pk.x = (unsigned int)hh[0][k] | ((unsigned int)hh[1][k] << 16);
                pk.y = (unsigned int)hh[2][k] | ((unsigned int)hh[3][k] << 16);
                *(uint2*)&RbufT[(c4 * 4 + k) * 20 + rg * 4] = pk;
            }
        }
    };

    ISSUE(0);
    STORE();
    __syncthreads();

    #pragma unroll
    for (int pass = 0; pass < 4; pass++) {
        if (pass < 3) ISSUE(pass + 1);   // loads in flight across GEMM1+combine+GEMM2
        // ---- GEMM1 (waves 0-3, K=256 slice each): scores 16 rows x 16 heads ----
        if (w < 4) {
            floatx4 acs = (floatx4)0.f;
            #pragma unroll
            for (int t = 0; t < 8; t++) {
                int kk = w * 8 + t;
                short8 a  = *(const short8*)(const void*)&Rbuf[lm * 1032 + kk * 32 + quad * 8];
                short8 bf = *(const short8*)(const void*)(qh + kk * 32 + quad * 8);
                acs = __builtin_amdgcn_mfma_f32_16x16x32_bf16(a, bf, acs, 0, 0, 0);
            }
            Sred[w][quad * 4 + 0][lm] = acs[0];
            Sred[w][quad * 4 + 1][lm] = acs[1];
            Sred[w][quad * 4 + 2][lm] = acs[2];
            Sred[w][quad * 4 + 3][lm] = acs[3];
        }
        __syncthreads();
        // ---- combine + exp + P (waves 0-3, one row per lane) ----
        if (w < 4) {
            int row = w * 4 + quad;
            float s = Sred[0][row][lm] + Sred[1][row][lm] + Sred[2][row][lm] + Sred[3][row][lm];
            float ex = __expf(s);          // SCALE folded into qkbf
            accden += ex;
            Pbuf[lm * 40 + row] = bf16c(ex);
        }
        __syncthreads();
        // ---- GEMM2 (all waves): num[h][e] += P(16h x 16r, K padded 32) @ R(16r x e) ----
        {
            short8 afr = {};
            if (quad < 2) afr = *(const short8*)(const void*)&Pbuf[lm * 40 + quad * 8];
            #pragma unroll
            for (int i = 0; i < 8; i++) {
                int e = (w * 8 + i) * 16 + lm;
                S8u bb2; bb2.s = (short8){};
                if (quad < 2) {
                    bb2.u2[0] = *(const uint2*)&RbufT[e * 20 + quad * 8];
                    bb2.u2[1] = *(const uint2*)&RbufT[e * 20 + quad * 8 + 4];
                }
                accn[i] = __builtin_amdgcn_mfma_f32_16x16x32_bf16(afr, bb2.s, accn[i], 0, 0, 0);
            }
        }
        __syncthreads();                  // all reads of pass done
        if (pass < 3) {
            STORE();                      // convert + write next pass (waits on its loads here)
            __syncthreads();
        }
    }
    // ---- epilogue: atomic f32 accumulation (accumulator stays L2-resident) ----
    {
        float* nb = num + (size_t)b * H * E;
        #pragma unroll
        for (int i = 0; i < 8; i++) {
            int e = (w * 8 + i) * 16 + lm;
            #pragma unroll
            for (int j = 0; j < 4; j++)
                atomicAdd(&nb[(size_t)(quad * 4 + j) * E + e], accn[i][j]);
        }
    }
    if (w < 4) {
        accden += __shfl_xor(accden, 16, 64);
        accden += __shfl_xor(accden, 32, 64);
        if (l < 16) denp[w][l] = accden;
    }
    __syncthreads();
    if (w == 0 && l < 16)
        atomicAdd(&den[(size_t)b * H + l], denp[0][l] + denp[1][l] + denp[2][l] + denp[3][l]);
}

// ---- 3. combine + ctx: block per (h, 4 batches); f32 num, no chunk loop ----
__global__ void k_pc(const float* __restrict__ num, const float* __restrict__ den,
                     const int* __restrict__ empty,
                     const float* __restrict__ w_in, const float* __restrict__ b_in,
                     float* __restrict__ ctx) {
    int h = blockIdx.x, b0 = blockIdx.y * 4, t = threadIdx.x;
    __shared__ float p_l[4][1024];
    __shared__ float cred[4][64][4];
    __shared__ float inv_l[4];
    #pragma unroll
    for (int k = 0; k < 2; k++) {
        int idx8 = k * 256 + t;
        int bb = idx8 >> 7, e8 = (idx8 & 127) * 8;
        float4 a0 = make_float4(0.f, 0.f, 0.f, 0.f), a1 = a0;
        if (!empty[b0 + bb]) {
            const float* src = num + ((size_t)(b0 + bb) * H + h) * E + e8;
            a0 = *(const float4*)src;
            a1 = *(const float4*)(src + 4);
        }
        *(float4*)&p_l[bb][e8]     = a0;
        *(float4*)&p_l[bb][e8 + 4] = a1;
    }
    if (t < 4) {
        float iv = 0.f;
        if (!empty[b0 + t]) iv = 1.0f / den[(size_t)(b0 + t) * H + h];
        inv_l[t] = iv;
    }
    __syncthreads();
    {
        int jj = t >> 2, part = t & 3;
        const float* wr = w_in + (size_t)(2 * E + h * HD + jj) * E + part * 256;
        float acc[4] = {0.f, 0.f, 0.f, 0.f};
        #pragma unroll 8
        for (int i = 0; i < 64; i++) {
            float4 wv = *(const float4*)(wr + i * 4);
            #pragma unroll
            for (int bb = 0; bb < 4; bb++)
                acc[bb] += dot4(wv, *(const float4*)&p_l[bb][part * 256 + i * 4]);
        }
        #pragma unroll
        for (int bb = 0; bb < 4; bb++) cred[bb][jj][part] = acc[bb];
    }
    __syncthreads();
    if (t < 64) {
        float bias = b_in[2 * E + h * HD + t];
        #pragma unroll
        for (int bb = 0; bb < 4; bb++) {
            float s = cred[bb][t][0] + cred[bb][t][1] + cred[bb][t][2] + cred[bb][t][3];
            ctx[(size_t)(b0 + bb) * E + h * HD + t] = inv_l[bb] * s + bias;
        }
    }
}

// ---- 4. out = origin_q + strength * (ctx @ Wout^T + bout), gated ----
__global__ void k_out(const float* __restrict__ model, const float* __restrict__ w_out,
                      const float* __restrict__ b_out, const float* __restrict__ ctx,
                      const int* __restrict__ mp, const int* __restrict__ empty,
                      const float* __restrict__ strength_p, float* __restrict__ out) {
    int w = threadIdx.x >> 6, l = threadIdx.x & 63;
    int j = blockIdx.x * 4 + w;
    int b0 = blockIdx.y * 8;
    const float* wr = w_out + (size_t)j * E;
    float4 wv[4];
    #pragma unroll
    for (int r = 0; r < 4; r++) wv[r] = *(const float4*)(wr + r * 256 + l * 4);
    float acc[8];
    #pragma unroll
    for (int bb = 0; bb < 8; bb++) {
        const float* src = ctx + (size_t)(b0 + bb) * E;
        float a = 0.f;
        #pragma unroll
        for (int r = 0; r < 4; r++) a += dot4(wv[r], *(const float4*)(src + r * 256 + l * 4));
        acc[bb] = a;
    }
    bfly8(acc);
    if (l < 8) {
        float myacc = acc[0];
        #pragma unroll
        for (int bb = 1; bb < 8; bb++) myacc = (l == bb) ? acc[bb] : myacc;
        int b = b0 + l;
        int m = mp[b];
        float orig = model[((size_t)(b * S + m)) * E + j];
        float bias = b_out[j];
        float st = strength_p[0];
        out[(size_t)b * E + j] = empty[b] ? orig : orig + st * (myacc + bias);
    }
}

extern "C" void kernel_launch(void* const* d_in, const int* in_sizes, int n_in,
                              void* d_out, int out_size, void* d_ws, size_t ws_size,
                              hipStream_t stream) {
    const float* model     = (const float*)d_in[0];
    const float* knowledge = (const float*)d_in[1];
    const float* w_in      = (const float*)d_in[2];
    const float* b_in      = (const float*)d_in[3];
    const float* w_out     = (const float*)d_in[4];
    const float* b_out     = (const float*)d_in[5];
    const float* strength  = (const float*)d_in[6];
    const int*   ids       = (const int*)d_in[7];
    const int*   empty     = (const int*)d_in[8];
    const int*   know_id   = (const int*)d_in[9];
    const int*   mask_id   = (const int*)d_in[10];
    float* out = (float*)d_out;

    float* ws  = (float*)d_ws;
    int*   mp  = (int*)d_ws;
    unsigned short* qkbf = (unsigned short*)(ws + W_QKBF);
    float* num = ws + W_NUM;
    float* den = ws + W_DEN;
    float* ctx = ws + W_CTX;

    k_qgen<<<dim3(H, 16), 256, 0, stream>>>(model, knowledge, ids, mask_id, know_id, mp,
                                            w_in, b_in, qkbf, num, den);
    k_attn<<<dim3(CATT, BS), 512, 0, stream>>>(model, knowledge, ids, know_id, empty,
                                               qkbf, num, den);
    k_pc<<<dim3(H, 16), 256, 0, stream>>>(num, den, empty, w_in, b_in, ctx);
    k_out<<<dim3(256, 8), 256, 0, stream>>>(model, w_out, b_out, ctx, mp, empty, strength, out);
}

// Round 7
// 267.509 us; speedup vs baseline: 1.0346x; 1.0346x over previous
//
#include <hip/hip_runtime.h>

#define BS 64
#define S  512
#define E  1024
#define H  16
#define HD 64
#define SCALE 0.125f   // 1/sqrt(64)
#define CATT 8         // attention chunks (64 rows each, 4 passes) — full-CU coverage w/ skip

// workspace float offsets
#define W_QKBF 66560      // bf16 qk (SCALE-folded): 64*16*1024 ushorts = 524288 float slots
#define W_NUM  1115136    // CATT partial chunks x BS*H*E bf16 (16 MB)
#define W_DEN  9503744    // CATT x BS*H f32
#define W_CTX  9511936    // BS*E f32

typedef __attribute__((ext_vector_type(8))) short short8;
typedef __attribute__((ext_vector_type(4))) float floatx4;

union S8u { uint2 u2[2]; short8 s; };

__device__ __forceinline__ unsigned short bf16c(float x) {
    unsigned int u = __float_as_uint(x);
    return (unsigned short)((u + 0x7fffu + ((u >> 16) & 1u)) >> 16);
}
__device__ __forceinline__ unsigned int pack_bf16(float a, float b) {
    return (unsigned int)bf16c(a) | ((unsigned int)bf16c(b) << 16);
}
__device__ __forceinline__ void fma4(float4& acc, float s, const float4& v) {
    acc.x += s * v.x; acc.y += s * v.y; acc.z += s * v.z; acc.w += s * v.w;
}
__device__ __forceinline__ float dot4(const float4& a, const float4& b) {
    return a.x * b.x + a.y * b.y + a.z * b.z + a.w * b.w;
}
__device__ __forceinline__ void bfly8(float* a) {
    #pragma unroll
    for (int off = 32; off > 0; off >>= 1) {
        #pragma unroll
        for (int i = 0; i < 8; i++) a[i] += __shfl_xor(a[i], off, 64);
    }
}

// ---- 1. fused prep + q + qk -> qkbf (bf16, SCALE folded). block per (h, 4 batches) ----
__global__ void k_qgen(const float* __restrict__ model, const float* __restrict__ knowledge,
                       const int* __restrict__ ids, const int* __restrict__ mask_id_p,
                       const int* __restrict__ kid_p, int* __restrict__ mp,
                       const float* __restrict__ w_in, const float* __restrict__ b_in,
                       unsigned short* __restrict__ qkbf) {
    int h = blockIdx.x, b0 = blockIdx.y * 4, t = threadIdx.x;
    __shared__ float qin_l[4][1024];
    __shared__ float qred[4][64][4];
    __shared__ float qs_l[4][64];
    __shared__ int best[4];
    if (t < 4) best[t] = S;
    __syncthreads();
    {   // scan: 64 threads per batch, 8 ids each
        int bb = t >> 6, ls = t & 63;
        int mid = mask_id_p[0];
        int found = S;
        #pragma unroll
        for (int k = 0; k < 8; k++) {
            int s = ls + k * 64;
            if (ids[(size_t)(b0 + bb) * S + s] == mid) found = min(found, s);
        }
        if (found < S) atomicMin(&best[bb], found);
    }
    __syncthreads();
    {   // gather q-input rows directly into LDS
        int kid = kid_p[0];
        #pragma unroll
        for (int bb = 0; bb < 4; bb++) {
            int m = (best[bb] == S) ? 0 : best[bb];
            bool isk = (ids[(size_t)(b0 + bb) * S + m] == kid);
            const float* qrow = isk ? knowledge + (size_t)(b0 + bb) * E
                                    : model + ((size_t)((b0 + bb) * S + m)) * E;
            *(float4*)&qin_l[bb][t * 4] = *(const float4*)(qrow + t * 4);
        }
        if (h == 0 && t < 4) mp[b0 + t] = (best[t] == S) ? 0 : best[t];
    }
    __syncthreads();
    {
        int d = t >> 2, part = t & 3;
        const float* wr = w_in + (size_t)(h * HD + d) * E + part * 256;
        float acc[4] = {0.f, 0.f, 0.f, 0.f};
        #pragma unroll 8
        for (int i = 0; i < 64; i++) {
            float4 wv = *(const float4*)(wr + i * 4);
            #pragma unroll
            for (int bb = 0; bb < 4; bb++)
                acc[bb] += dot4(wv, *(const float4*)&qin_l[bb][part * 256 + i * 4]);
        }
        #pragma unroll
        for (int bb = 0; bb < 4; bb++) qred[bb][d][part] = acc[bb];
    }
    __syncthreads();
    if (t < 64) {
        float bias = b_in[h * HD + t];
        #pragma unroll
        for (int bb = 0; bb < 4; bb++)
            qs_l[bb][t] = qred[bb][t][0] + qred[bb][t][1] + qred[bb][t][2] + qred[bb][t][3] + bias;
    }
    __syncthreads();
    {
        int e0 = t * 4;
        const float* wk = w_in + (size_t)(E + h * HD) * E + e0;
        float4 acc[4];
        #pragma unroll
        for (int bb = 0; bb < 4; bb++) acc[bb] = make_float4(0.f, 0.f, 0.f, 0.f);
        #pragma unroll 8
        for (int d = 0; d < HD; d++) {
            float4 wv = *(const float4*)(wk + (size_t)d * E);
            #pragma unroll
            for (int bb = 0; bb < 4; bb++) fma4(acc[bb], qs_l[bb][d], wv);
        }
        #pragma unroll
        for (int bb = 0; bb < 4; bb++) {
            uint2 pk;
            pk.x = pack_bf16(acc[bb].x * SCALE, acc[bb].y * SCALE);
            pk.y = pack_bf16(acc[bb].z * SCALE, acc[bb].w * SCALE);
            *(uint2*)&qkbf[((size_t)(b0 + bb) * H + h) * E + e0] = pk;
        }
    }
}

// ---- 2. fused attention via MFMA; skips batches whose result is discarded ----
// block per (chunk c of 64 rows, batch b); 512 thr (8 waves); 4 passes x 16 rows.
__global__ __launch_bounds__(512, 4) void k_attn(
    const float* __restrict__ model, const float* __restrict__ knowledge,
    const int* __restrict__ ids, const int* __restrict__ kid_p,
    const int* __restrict__ empty,
    const unsigned short* __restrict__ qkbf, unsigned short* __restrict__ num,
    float* __restrict__ den) {
    int c = blockIdx.x, b = blockIdx.y;
    if (empty[b]) return;   // uniform exit before any barrier: result is discarded by k_out

    __shared__ __align__(16) unsigned char Ubuf[73984];   // Rbuf(33024)+RbufT(40960) | TbufH(32768)
    unsigned short* Rbuf  = (unsigned short*)Ubuf;           // 16 rows x 1032 (GEMM1 A)
    unsigned short* RbufT = (unsigned short*)(Ubuf + 33024); // 1024 e x 20 (GEMM2 B)
    unsigned short* TbufH = (unsigned short*)Ubuf;           // epilogue: [h][e] stride 1024, bf16
    __shared__ unsigned short Pbuf[16 * 40];
    __shared__ float Sred[4][16][17];
    __shared__ float denp[4][16];
    __shared__ unsigned long long kmask_s;

    int tid = threadIdx.x;
    int w = tid >> 6, l = tid & 63;
    int quad = l >> 4, lm = l & 15;
    int s0 = c * 64;

    if (w == 0) {
        int id = ids[b * S + s0 + l];
        unsigned long long mk = __ballot(id == kid_p[0]);
        if (l == 0) kmask_s = mk;
    }
    floatx4 accn[8];
    #pragma unroll
    for (int i = 0; i < 8; i++) accn[i] = (floatx4)0.f;
    float accden = 0.f;
    const float* kb = knowledge + (size_t)b * E;
    const float* mb = model + (size_t)b * S * E;
    const unsigned short* qh = qkbf + ((size_t)b * H + lm) * E;
    __syncthreads();
    unsigned long long kmask = kmask_s;

    // staging geometry: thread owns (row-group rgA, rgA+2) x col-quad c4
    int rgA = tid >> 8;        // 0 or 1
    int c4  = tid & 255;       // float4 column index

    float4 st[8];              // 2 units x 4 rows, held across compute (T14)

    auto ISSUE = [&](int pass) {
        int rb = pass * 16;
        #pragma unroll
        for (int j = 0; j < 4; j++) {
            int row = rb + rgA * 4 + j;
            const float* rp = ((kmask >> row) & 1ull) ? kb : mb + (size_t)(s0 + row) * E;
            st[j] = *(const float4*)(rp + c4 * 4);
        }
        #pragma unroll
        for (int j = 0; j < 4; j++) {
            int row = rb + (rgA + 2) * 4 + j;
            const float* rp = ((kmask >> row) & 1ull) ? kb : mb + (size_t)(s0 + row) * E;
            st[4 + j] = *(const float4*)(rp + c4 * 4);
        }
    };
    auto STORE = [&]() {
        #pragma unroll
        for (int u = 0; u < 2; u++) {
            int rg = rgA + u * 2;
            unsigned short hh[4][4];
            #pragma unroll
            for (int j = 0; j < 4; j++) {
                float4 v = st[u * 4 + j];
                hh[j][0] = bf16c(v.x); hh[j][1] = bf16c(v.y);
                hh[j][2] = bf16c(v.z); hh[j][3] = bf16c(v.w);
            }
            #pragma unroll
            for (int j = 0; j < 4; j++) {          // row-major Rbuf: 4 consecutive cols
                uint2 pk;
                pk.x = (unsigned int)hh[j][0] | ((unsigned int)hh[j][1] << 16);
                pk.y = (unsigned int)hh[j][2] | ((unsigned int)hh[j][3] << 16);
                *(uint2*)&Rbuf[(rg * 4 + j) * 1032 + c4 * 4] = pk;
            }
            #pragma unroll
            for (int k = 0; k < 4; k++) {          // transposed RbufT: 4 consecutive rows
                uint2 pk;
                pk.x = (unsigned int)hh[0][k] | ((unsigned int)hh[1][k] << 16);
                pk.y = (unsigned int)hh[2][k] | ((unsigned int)hh[3][k] << 16);
                *(uint2*)&RbufT[(c4 * 4 + k) * 20 + rg * 4] = pk;
            }
        }
    };

    ISSUE(0);
    STORE();
    __syncthreads();

    #pragma unroll
    for (int pass = 0; pass < 4; pass++) {
        if (pass < 3) ISSUE(pass + 1);   // loads in flight across GEMM1+combine+GEMM2
        // ---- GEMM1 (waves 0-3, K=256 slice each): scores 16 rows x 16 heads ----
        if (w < 4) {
            floatx4 acs = (floatx4)0.f;
            #pragma unroll
            for (int t = 0; t < 8; t++) {
                int kk = w * 8 + t;
                short8 a  = *(const short8*)(const void*)&Rbuf[lm * 1032 + kk * 32 + quad * 8];
                short8 bf = *(const short8*)(const void*)(qh + kk * 32 + quad * 8);
                acs = __builtin_amdgcn_mfma_f32_16x16x32_bf16(a, bf, acs, 0, 0, 0);
            }
            Sred[w][quad * 4 + 0][lm] = acs[0];
            Sred[w][quad * 4 + 1][lm] = acs[1];
            Sred[w][quad * 4 + 2][lm] = acs[2];
            Sred[w][quad * 4 + 3][lm] = acs[3];
        }
        __syncthreads();
        // ---- combine + exp + P (waves 0-3, one row per lane) ----
        if (w < 4) {
            int row = w * 4 + quad;
            float s = Sred[0][row][lm] + Sred[1][row][lm] + Sred[2][row][lm] + Sred[3][row][lm];
            float ex = __expf(s);          // SCALE folded into qkbf
            accden += ex;
            Pbuf[lm * 40 + row] = bf16c(ex);
        }
        __syncthreads();
        // ---- GEMM2 (all waves): num[h][e] += P(16h x 16r, K padded 32) @ R(16r x e) ----
        {
            short8 afr = {};
            if (quad < 2) afr = *(const short8*)(const void*)&Pbuf[lm * 40 + quad * 8];
            #pragma unroll
            for (int i = 0; i < 8; i++) {
                int e = (w * 8 + i) * 16 + lm;
                S8u bb2; bb2.s = (short8){};
                if (quad < 2) {
                    bb2.u2[0] = *(const uint2*)&RbufT[e * 20 + quad * 8];
                    bb2.u2[1] = *(const uint2*)&RbufT[e * 20 + quad * 8 + 4];
                }
                accn[i] = __builtin_amdgcn_mfma_f32_16x16x32_bf16(afr, bb2.s, accn[i], 0, 0, 0);
            }
        }
        __syncthreads();                  // all reads of pass done
        if (pass < 3) {
            STORE();                      // convert + write next pass (waits on its loads here)
            __syncthreads();
        }
    }
    // ---- epilogue: pack accn to bf16, transpose through LDS, store coalesced ----
    #pragma unroll
    for (int i = 0; i < 8; i++) {
        int e = (w * 8 + i) * 16 + lm;
        TbufH[(quad * 4 + 0) * 1024 + e] = bf16c(accn[i][0]);
        TbufH[(quad * 4 + 1) * 1024 + e] = bf16c(accn[i][1]);
        TbufH[(quad * 4 + 2) * 1024 + e] = bf16c(accn[i][2]);
        TbufH[(quad * 4 + 3) * 1024 + e] = bf16c(accn[i][3]);
    }
    if (w < 4) {
        accden += __shfl_xor(accden, 16, 64);
        accden += __shfl_xor(accden, 32, 64);
        if (l < 16) denp[w][l] = accden;
    }
    __syncthreads();
    if (w == 0 && l < 16)
        den[(size_t)(c * BS + b) * H + l] = denp[0][l] + denp[1][l] + denp[2][l] + denp[3][l];
    // 16*1024 shorts = 2048 uint4; 4 iters x 512 threads
    uint4* numv = (uint4*)(num + ((size_t)(c * BS + b) * H) * E);
    const uint4* tb = (const uint4*)TbufH;
    #pragma unroll
    for (int k = 0; k < 4; k++)
        numv[k * 512 + tid] = tb[k * 512 + tid];
}

// ---- 3. combine + ctx: block per (h, 4 batches); skips empty batches ----
__global__ void k_pc(const unsigned short* __restrict__ num, const float* __restrict__ den,
                     const int* __restrict__ empty,
                     const float* __restrict__ w_in, const float* __restrict__ b_in,
                     float* __restrict__ ctx) {
    int h = blockIdx.x, b0 = blockIdx.y * 4, t = threadIdx.x;
    __shared__ float p_l[4][1024];
    __shared__ float cred[4][64][4];
    __shared__ float inv_l[4];
    #pragma unroll
    for (int k = 0; k < 2; k++) {
        int idx8 = k * 256 + t;
        int bb = idx8 >> 7, e8 = (idx8 & 127) * 8;
        float a0 = 0.f, a1 = 0.f, a2 = 0.f, a3 = 0.f, a4 = 0.f, a5 = 0.f, a6 = 0.f, a7 = 0.f;
        if (!empty[b0 + bb]) {
            #pragma unroll
            for (int cc = 0; cc < CATT; cc++) {
                uint4 v = *(const uint4*)(num + (((size_t)(cc * BS + b0 + bb) * H + h) * E) + e8);
                a0 += __uint_as_float(v.x << 16);
                a1 += __uint_as_float(v.x & 0xffff0000u);
                a2 += __uint_as_float(v.y << 16);
                a3 += __uint_as_float(v.y & 0xffff0000u);
                a4 += __uint_as_float(v.z << 16);
                a5 += __uint_as_float(v.z & 0xffff0000u);
                a6 += __uint_as_float(v.w << 16);
                a7 += __uint_as_float(v.w & 0xffff0000u);
            }
        }
        *(float4*)&p_l[bb][e8]     = make_float4(a0, a1, a2, a3);
        *(float4*)&p_l[bb][e8 + 4] = make_float4(a4, a5, a6, a7);
    }
    if (t < 4) {
        float iv = 0.f;
        if (!empty[b0 + t]) {
            float ds = 0.f;
            for (int cc = 0; cc < CATT; cc++) ds += den[(size_t)(cc * BS + b0 + t) * H + h];
            iv = 1.0f / ds;
        }
        inv_l[t] = iv;
    }
    __syncthreads();
    {
        int jj = t >> 2, part = t & 3;
        const float* wr = w_in + (size_t)(2 * E + h * HD + jj) * E + part * 256;
        float acc[4] = {0.f, 0.f, 0.f, 0.f};
        #pragma unroll 8
        for (int i = 0; i < 64; i++) {
            float4 wv = *(const float4*)(wr + i * 4);
            #pragma unroll
            for (int bb = 0; bb < 4; bb++)
                acc[bb] += dot4(wv, *(const float4*)&p_l[bb][part * 256 + i * 4]);
        }
        #pragma unroll
        for (int bb = 0; bb < 4; bb++) cred[bb][jj][part] = acc[bb];
    }
    __syncthreads();
    if (t < 64) {
        float bias = b_in[2 * E + h * HD + t];
        #pragma unroll
        for (int bb = 0; bb < 4; bb++) {
            float s = cred[bb][t][0] + cred[bb][t][1] + cred[bb][t][2] + cred[bb][t][3];
            ctx[(size_t)(b0 + bb) * E + h * HD + t] = inv_l[bb] * s + bias;
        }
    }
}

// ---- 4. out = origin_q + strength * (ctx @ Wout^T + bout), gated ----
__global__ void k_out(const float* __restrict__ model, const float* __restrict__ w_out,
                      const float* __restrict__ b_out, const float* __restrict__ ctx,
                      const int* __restrict__ mp, const int* __restrict__ empty,
                      const float* __restrict__ strength_p, float* __restrict__ out) {
    int w = threadIdx.x >> 6, l = threadIdx.x & 63;
    int j = blockIdx.x * 4 + w;
    int b0 = blockIdx.y * 8;
    const float* wr = w_out + (size_t)j * E;
    float4 wv[4];
    #pragma unroll
    for (int r = 0; r < 4; r++) wv[r] = *(const float4*)(wr + r * 256 + l * 4);
    float acc[8];
    #pragma unroll
    for (int bb = 0; bb < 8; bb++) {
        const float* src = ctx + (size_t)(b0 + bb) * E;
        float a = 0.f;
        #pragma unroll
        for (int r = 0; r < 4; r++) a += dot4(wv[r], *(const float4*)(src + r * 256 + l * 4));
        acc[bb] = a;
    }
    bfly8(acc);
    if (l < 8) {
        float myacc = acc[0];
        #pragma unroll
        for (int bb = 1; bb < 8; bb++) myacc = (l == bb) ? acc[bb] : myacc;
        int b = b0 + l;
        int m = mp[b];
        float orig = model[((size_t)(b * S + m)) * E + j];
        float bias = b_out[j];
        float st = strength_p[0];
        out[(size_t)b * E + j] = empty[b] ? orig : orig + st * (myacc + bias);
    }
}

extern "C" void kernel_launch(void* const* d_in, const int* in_sizes, int n_in,
                              void* d_out, int out_size, void* d_ws, size_t ws_size,
                              hipStream_t stream) {
    const float* model     = (const float*)d_in[0];
    const float* knowledge = (const float*)d_in[1];
    const float* w_in      = (const float*)d_in[2];
    const float* b_in      = (const float*)d_in[3];
    const float* w_out     = (const float*)d_in[4];
    const float* b_out     = (const float*)d_in[5];
    const float* strength  = (const float*)d_in[6];
    const int*   ids       = (const int*)d_in[7];
    const int*   empty     = (const int*)d_in[8];
    const int*   know_id   = (const int*)d_in[9];
    const int*   mask_id   = (const int*)d_in[10];
    float* out = (float*)d_out;

    float* ws  = (float*)d_ws;
    int*   mp  = (int*)d_ws;
    unsigned short* qkbf = (unsigned short*)(ws + W_QKBF);
    unsigned short* num  = (unsigned short*)(ws + W_NUM);
    float* den = ws + W_DEN;
    float* ctx = ws + W_CTX;

    k_qgen<<<dim3(H, 16), 256, 0, stream>>>(model, knowledge, ids, mask_id, know_id, mp,
                                            w_in, b_in, qkbf);
    k_attn<<<dim3(CATT, BS), 512, 0, stream>>>(model, knowledge, ids, know_id, empty,
                                               qkbf, num, den);
    k_pc<<<dim3(H, 16), 256, 0, stream>>>(num, den, empty, w_in, b_in, ctx);
    k_out<<<dim3(256, 8), 256, 0, stream>>>(model, w_out, b_out, ctx, mp, empty, strength, out);
}